// Round 7
// baseline (2091.496 us; speedup 1.0000x reference)
//
#include <hip/hip_runtime.h>
#include <math.h>

// ---------------------------------------------------------------------------
// RNN_63153199120819 — Round 17: group 16->8 + barrier-overlapped u-half GEMM.
// Evidence: phase = ~5-6us clock-independent latency (LLC barrier + skew +
// L2 stage) + ~5us clocked work @~730MHz (DVFS); component shaving is neutral.
// Structural changes:
//  (a) 32 groups x 8 blocks x 32 batch rows: no B-frag redundancy, stage
//      traffic halved (2x16KB), barrier fan-in 8, smaller skew tail.
//  (b) layer-0's u(t+1) K-half (32 MFMA + u loads) issues BEFORE the poll —
//      fills the barrier wait with work. (u(t+1) overwrite by peers is gated
//      on our end-of-phase publish => pre-poll reads are race-free.)
// LDS 66.5KB used, 96KB forced (pin 1 block/CU for XCD-rank discovery).
// Barrier protocol (per-slot LLC atomics), sc0 staging, swizzle, per-wave
// cells: all R16-proven, re-indexed.
// ---------------------------------------------------------------------------

namespace {
constexpr int kT   = 128;
constexpr int kB   = 1024;
constexpr int kLag = 6;
constexpr int kH   = 256;
constexpr int kTc  = 32;          // MLP time chunk
constexpr int kMc  = kTc * kB;    // 32768 rows / chunk
constexpr int kGS  = 132;         // gl row stride (f32) for 128 gate cols
constexpr int kLdsForce = 98304;  // force 1 block/CU (rank discovery relies on it)
constexpr int kRankMain = 4096;   // cnt[] uint idx: flags [0,4096), ranks 4096+
constexpr int kCntUints = 16384;  // zeroed: 64KB
}

typedef _Float16 half8 __attribute__((ext_vector_type(8)));
typedef _Float16 half4 __attribute__((ext_vector_type(4)));
typedef float f32x4 __attribute__((ext_vector_type(4)));
typedef unsigned long long u64;

__device__ __forceinline__ float sigm(float x) {
    return 1.f / (1.f + exp2f(-1.4426950408889634f * x));
}
__device__ __forceinline__ float tanh_(float x) {
    return 2.f / (1.f + exp2f(-2.8853900817779268f * x)) - 1.f;
}

__device__ __forceinline__ half8 pack(u64 a, u64 b) {
    union { u64 u[2]; half8 h; } r;
    r.u[0] = a; r.u[1] = b;
    return r.h;
}

// ---- inline-asm memory ops ------------------------------------------------
__device__ __forceinline__ void ld_l2(half8& d, const _Float16* p) {
    asm volatile("global_load_dwordx4 %0, %1, off sc0"
                 : "=v"(d) : "v"(p) : "memory");
}
#define WAITCNT_HOLD4(A, B)                                                   \
    asm volatile("s_waitcnt vmcnt(0)"                                         \
        : "+v"(A[0]), "+v"(A[1]), "+v"(B[0]), "+v"(B[1]))

// ---------------- prep kernels ---------------------------------------------
__global__ __launch_bounds__(256)
void zero_fill(unsigned int* __restrict__ p)
{
    p[blockIdx.x * 256 + threadIdx.x] = 0u;
}

__global__ __launch_bounds__(256)
void cvt_f2h(const float* __restrict__ s, _Float16* __restrict__ d)
{
    const int i = blockIdx.x * 256 + threadIdx.x;
    d[i] = (_Float16)s[i];
}

// gate-interleaved Wc: new row r = hcol*4 + g  <-  old row g*256 + hcol.
__global__ __launch_bounds__(256)
void build_wcat3(const float* __restrict__ Wih, const float* __restrict__ Whh,
                 _Float16* __restrict__ d)
{
    const int i = blockIdx.x * 256 + threadIdx.x;   // over 1024*512
    const int row = i >> 9, col = i & 511;
    const int src = (row & 3) * 256 + (row >> 2);
    const float v = (col < 256) ? Wih[src * 256 + col] : Whh[src * 256 + col - 256];
    d[i] = (_Float16)v;
}

__global__ __launch_bounds__(256)
void add_bias(const float* __restrict__ a, const float* __restrict__ b,
              float* __restrict__ d)
{
    const int i = blockIdx.x * 256 + threadIdx.x;
    d[i] = a[i] + b[i];
}

// ---------------- first layer: u1 = relu(x @ Wi1^T + bi1), K=6, fp16 out ---
__global__ __launch_bounds__(256)
void in_mlp1(const float* __restrict__ x, const float* __restrict__ Wi1,
             const float* __restrict__ bi1, _Float16* __restrict__ out)
{
    const int idx = blockIdx.x * 256 + threadIdx.x;   // over Mc*H
    const int col = idx & (kH - 1);
    const int row = idx >> 8;
    const float* xr = x + (size_t)row * kLag;
    const float* w  = Wi1 + col * kLag;
    float s = bi1[col];
#pragma unroll
    for (int k = 0; k < kLag; ++k) s = fmaf(xr[k], w[k], s);
    out[idx] = (_Float16)fmaxf(s, 0.f);
}

// ---------------- fp16 MFMA GEMM v2 (unchanged, validated) -----------------
__global__ __launch_bounds__(256)
void gemm_h16(const _Float16* __restrict__ A, const _Float16* __restrict__ W,
              const float* __restrict__ bias, _Float16* __restrict__ C)
{
    const int tid = threadIdx.x;
    const int w = tid >> 6, lane = tid & 63, q = lane >> 4, l15 = lane & 15;
    const int n0 = blockIdx.x * 64;
    const int r0 = blockIdx.y * 128 + w * 32;

    half8 bf[4][8];
#pragma unroll
    for (int nt = 0; nt < 4; ++nt)
#pragma unroll
        for (int kk = 0; kk < 8; ++kk)
            bf[nt][kk] = *(const half8*)(W + (size_t)(n0 + nt * 16 + l15) * 256
                                         + kk * 32 + q * 8);
    float bz[4];
#pragma unroll
    for (int nt = 0; nt < 4; ++nt) bz[nt] = bias[n0 + nt * 16 + l15];

#pragma unroll
    for (int rt = 0; rt < 2; ++rt) {
        const _Float16* arow = A + (size_t)(r0 + rt * 16 + l15) * 256 + q * 8;
        half8 af[8];
#pragma unroll
        for (int kk = 0; kk < 8; ++kk) af[kk] = *(const half8*)(arow + kk * 32);
        f32x4 acc[4];
#pragma unroll
        for (int nt = 0; nt < 4; ++nt)
            acc[nt] = (f32x4){bz[nt], bz[nt], bz[nt], bz[nt]};
#pragma unroll
        for (int kk = 0; kk < 8; ++kk)
#pragma unroll
            for (int nt = 0; nt < 4; ++nt)
                acc[nt] = __builtin_amdgcn_mfma_f32_16x16x32_f16(
                    af[kk], bf[nt][kk], acc[nt], 0, 0, 0);
#pragma unroll
        for (int nt = 0; nt < 4; ++nt)
#pragma unroll
            for (int r = 0; r < 4; ++r) {
                const float v = fmaxf(acc[nt][r], 0.f);
                C[(size_t)(r0 + rt * 16 + q * 4 + r) * 256 + n0 + nt * 16 + l15]
                    = (_Float16)v;
            }
    }
}

// ---------------- persistent LSTM helpers ----------------------------------
// wait: poll all 8 group slots in parallel (agent loads, LLC).
__device__ __forceinline__ void waitpeers(const unsigned int* __restrict__ fb,
                                          unsigned int target, int tid)
{
    if (tid < 64) {
        const unsigned int* fp = fb + (tid & 7) * 16;   // 64B-padded slots
        unsigned int v;
        do {
            v = __hip_atomic_load(fp, __ATOMIC_RELAXED,
                                  __HIP_MEMORY_SCOPE_AGENT);
        } while (__any(v < target));
    }
    __syncthreads();
}

__device__ __forceinline__ void gather_lo(const _Float16* lo, int row, int q,
                                          u64* ua)
{
    const u64* plo = (const u64*)(lo + (size_t)row * 256 + q * 8);
#pragma unroll
    for (int kk = 0; kk < 8; ++kk) {
        ua[2*kk]   = plo[kk*8];
        ua[2*kk+1] = plo[kk*8 + 1];
    }
}

// MFMA C layout: col=l15, row=q*4+r. Wave's gate cols: wl*32 + tile*16 + l15.
__device__ __forceinline__ void gstore(float* __restrict__ gl, int rt, int wl,
                                       int q, int l15,
                                       const f32x4& a0, const f32x4& a1)
{
#pragma unroll
    for (int r = 0; r < 4; ++r) {
        gl[(rt*16 + q*4 + r) * kGS + wl*32 + l15]      = a0[r];
        gl[(rt*16 + q*4 + r) * kGS + wl*32 + 16 + l15] = a1[r];
    }
}

// per-wave cells: 4 cells/lane; gates at gl[grow][gcb + c*4 + g] (f32x4).
__device__ __forceinline__ void cells_wave(const float* __restrict__ gl,
    int grow, int gcb, const float* __restrict__ bs, float* __restrict__ cst,
    _Float16* __restrict__ hout, _Float16* __restrict__ uout)
{
    const float* gr = gl + grow * kGS + gcb;
    half4 hv;
#pragma unroll
    for (int c = 0; c < 4; ++c) {
        const f32x4 g4 = *(const f32x4*)(gr + c * 4);   // gates i,f,g,o
        const float gi = g4[0] + bs[c*4 + 0];
        const float gf = g4[1] + bs[c*4 + 1];
        const float gg = g4[2] + bs[c*4 + 2];
        const float go = g4[3] + bs[c*4 + 3];
        const float c2 = sigm(gf) * cst[c] + sigm(gi) * tanh_(gg);
        cst[c] = c2;
        hv[c] = (_Float16)(sigm(go) * tanh_(c2));
    }
    *(half4*)hout = hv;
    if (uout) {
        const _Float16 z = (_Float16)0.f;
        half4 uv;
#pragma unroll
        for (int c = 0; c < 4; ++c) uv[c] = hv[c] > z ? hv[c] : z;
        *(half4*)uout = uv;
    }
}

// ---------------- persistent LSTM kernel -----------------------------------
// 256 blocks = 32 groups x 8. Group bi owns batch rows [bi*32, bi*32+32).
// Block js owns h-cols [js*32, js*32+32) of both layers (gate rows js*128+..).
__global__ __launch_bounds__(512, 2)
void lstm_all(_Float16* __restrict__ ubuf,
              const _Float16* __restrict__ Wc0, const _Float16* __restrict__ Wc1,
              const float* __restrict__ bc0, const float* __restrict__ bc1,
              _Float16* __restrict__ h0b, _Float16* __restrict__ h1b,
              unsigned int* __restrict__ cnt)
{
    extern __shared__ char lds[];
    char* pH0  = lds;                     // 16KB swizzled h0(t) panel (32x512B)
    char* pH1  = lds + 16384;             // 16KB swizzled h1(t-1) panel
    float* gl0 = (float*)(lds + 32768);   // [32][kGS] layer-0 gates
    float* gl1 = gl0 + 32 * kGS;          // [32][kGS] layer-1 gates

    const int tid = threadIdx.x;
    const int w = tid >> 6, lane = tid & 63, q = lane >> 4, l15 = lane & 15;
    const int wl = w & 3;                 // wave's col-slice within layer
    const int lyr = (w < 4) ? 1 : 0;      // wave's layer

    // ---- XCD discovery: 1 block/CU (forced LDS) => 32 blocks/XCD ----
    __shared__ int sh_bi, sh_js;
    if (tid == 0) {
        unsigned int xcd = __builtin_amdgcn_s_getreg(20 | (31 << 11)) & 7u;
        unsigned int rank = __hip_atomic_fetch_add(cnt + kRankMain + xcd * 16, 1u,
            __ATOMIC_RELAXED, __HIP_MEMORY_SCOPE_AGENT);
        sh_bi = (int)(xcd * 4 + (rank >> 3));
        sh_js = (int)(rank & 7);
    }
    __syncthreads();
    const int bi = sh_bi, js = sh_js;
    unsigned int* fb    = cnt + (size_t)bi * 128;   // 8 slots x 64B
    unsigned int* fslot = fb + js * 16;

    // ---- B-fragments: gate rows js*128 + wl*32 + tile*16 + l15 ----
    const _Float16* WcL = lyr ? Wc1 : Wc0;
    half8 Bf0[16], Bf1[16];
    {
        const _Float16* wr0 = WcL + (size_t)(js*128 + wl*32 + l15) * 512 + q * 8;
        const _Float16* wr1 = wr0 + (size_t)16 * 512;
#pragma unroll
        for (int kk = 0; kk < 16; ++kk) {
            Bf0[kk] = *(const half8*)(wr0 + kk * 32);
            Bf1[kk] = *(const half8*)(wr1 + kk * 32);
        }
    }

    // ---- staging dsts: 2 rounds x 16B/thread over 16KB panel ----
    int sdst[2];
#pragma unroll
    for (int r = 0; r < 2; ++r) {
        const int L   = tid * 16 + r * 8192;
        const int row = L >> 9;
        const int c   = L & 511;
        sdst[r] = row * 512 + (c ^ ((row & 15) << 4) ^ ((row & 1) << 8));
    }

    // ---- per-lane cell geometry / biases / state ----
    const int grow = lane >> 1;                     // batch row 0..31
    const int gcb  = wl*32 + (lane & 1) * 16;       // gl gate-col base
    const int hcb  = js*32 + wl*8 + (lane & 1) * 4; // global h-col base
    const float* bcL = lyr ? bc1 : bc0;
    float bs[16];
#pragma unroll
    for (int c = 0; c < 4; ++c)
#pragma unroll
        for (int g = 0; g < 4; ++g)
            bs[c*4 + g] = bcL[g * 256 + hcb + c];
    float cst[4] = {0.f, 0.f, 0.f, 0.f};
    const size_t rbase = (size_t)bi * 32 * 256;
    const size_t coff  = rbase + (size_t)grow * 256 + hcb;  // per-thread h/u offset

    // ---- prologue: h0(0) = cell(u(0)-half @ W0 + bias), h=0 ----
    if (lyr == 0) {
#pragma unroll
        for (int rt = 0; rt < 2; ++rt) {
            u64 ua[16];
            gather_lo(ubuf + rbase, rt*16 + l15, q, ua);
            f32x4 a0 = {0.f,0.f,0.f,0.f}, a1 = {0.f,0.f,0.f,0.f};
#pragma unroll
            for (int kk = 0; kk < 8; ++kk) {
                const half8 af = pack(ua[2*kk], ua[2*kk+1]);
                a0 = __builtin_amdgcn_mfma_f32_16x16x32_f16(af, Bf0[kk], a0, 0,0,0);
                a1 = __builtin_amdgcn_mfma_f32_16x16x32_f16(af, Bf1[kk], a1, 0,0,0);
            }
            gstore(gl0, rt, wl, q, l15, a0, a1);
        }
        cells_wave(gl0, grow, gcb, bs, cst, (_Float16*)(h0b + coff), nullptr);
    }
    asm volatile("s_waitcnt vmcnt(0)" ::: "memory");
    __syncthreads();
    if (tid == 0)
        __hip_atomic_fetch_add(fslot, 1u, __ATOMIC_RELAXED,
                               __HIP_MEMORY_SCOPE_AGENT);

    // ---- phases: t computes h1(t) (waves 0-3) + h0(t+1) (waves 4-7) ----
    for (int t = 0; t < kT; ++t) {
        const size_t p  = (size_t)(t & 1) * kB * 256;        // h0(t) parity
        const size_t pn = (size_t)((t & 1) ^ 1) * kB * 256;  // h1(t-1) parity
        const bool hasB = (t < kT - 1);

        // -- pre-poll: layer-0's u(t+1) K-half (peer-independent).
        //    Accumulators persist across the barrier.
        f32x4 aA0 = {0.f,0.f,0.f,0.f}, aA1 = {0.f,0.f,0.f,0.f};
        f32x4 aB0 = {0.f,0.f,0.f,0.f}, aB1 = {0.f,0.f,0.f,0.f};
        if (lyr == 0 && hasB) {
            const _Float16* u = ubuf + (size_t)(t + 1) * kB * 256 + rbase;
            {
                const _Float16* pu = u + (size_t)(l15) * 256 + q * 8;
                half8 uf[8];
#pragma unroll
                for (int kk = 0; kk < 8; ++kk) uf[kk] = *(const half8*)(pu + kk * 32);
#pragma unroll
                for (int kk = 0; kk < 8; ++kk) {
                    aA0 = __builtin_amdgcn_mfma_f32_16x16x32_f16(uf[kk], Bf0[kk], aA0, 0,0,0);
                    aA1 = __builtin_amdgcn_mfma_f32_16x16x32_f16(uf[kk], Bf1[kk], aA1, 0,0,0);
                }
            }
            {
                const _Float16* pu = u + (size_t)(16 + l15) * 256 + q * 8;
                half8 uf[8];
#pragma unroll
                for (int kk = 0; kk < 8; ++kk) uf[kk] = *(const half8*)(pu + kk * 32);
#pragma unroll
                for (int kk = 0; kk < 8; ++kk) {
                    aB0 = __builtin_amdgcn_mfma_f32_16x16x32_f16(uf[kk], Bf0[kk], aB0, 0,0,0);
                    aB1 = __builtin_amdgcn_mfma_f32_16x16x32_f16(uf[kk], Bf1[kk], aB1, 0,0,0);
                }
            }
        }

        // -- group barrier: peers published phase t+1 (h0(t), h1(t-1) ready)
        waitpeers(fb, (unsigned)(t + 1), tid);

        // -- stage h0(t), h1(t-1) panels (sc0 -> XCD L2), swizzled
        {
            half8 s0[2], s1h[2];
            const char* b0 = (const char*)(h0b + p  + rbase);
            const char* b1 = (const char*)(h1b + pn + rbase);
#pragma unroll
            for (int r = 0; r < 2; ++r) {
                ld_l2(s0[r],  (const _Float16*)(b0 + tid * 16 + r * 8192));
                ld_l2(s1h[r], (const _Float16*)(b1 + tid * 16 + r * 8192));
            }
            WAITCNT_HOLD4(s0, s1h);
#pragma unroll
            for (int r = 0; r < 2; ++r) {
                *(half8*)(pH0 + sdst[r]) = s0[r];
                *(half8*)(pH1 + sdst[r]) = s1h[r];
            }
        }
        __syncthreads();

        // -- post-poll GEMM halves + per-wave cells
        if (lyr == 1) {
#pragma unroll
            for (int rt = 0; rt < 2; ++rt) {
                const int row = rt*16 + l15;
                const int xr  = ((row & 15) << 4) ^ ((row & 1) << 8);
                const int rb  = row * 512;
                f32x4 a0 = {0.f,0.f,0.f,0.f}, a1 = {0.f,0.f,0.f,0.f};
#pragma unroll
                for (int kk = 0; kk < 8; ++kk) {
                    const int off = rb + ((q * 16 + kk * 64) ^ xr);
                    const half8 alo = *(const half8*)(pH0 + off);   // h0(t)
                    const half8 ahi = *(const half8*)(pH1 + off);   // h1(t-1)
                    a0 = __builtin_amdgcn_mfma_f32_16x16x32_f16(alo, Bf0[kk],     a0, 0,0,0);
                    a1 = __builtin_amdgcn_mfma_f32_16x16x32_f16(alo, Bf1[kk],     a1, 0,0,0);
                    a0 = __builtin_amdgcn_mfma_f32_16x16x32_f16(ahi, Bf0[8 + kk], a0, 0,0,0);
                    a1 = __builtin_amdgcn_mfma_f32_16x16x32_f16(ahi, Bf1[8 + kk], a1, 0,0,0);
                }
                gstore(gl1, rt, wl, q, l15, a0, a1);
            }
            cells_wave(gl1, grow, gcb, bs, cst,
                       (_Float16*)(h1b + p + coff),
                       (_Float16*)(ubuf + (size_t)t * kB * 256 + coff));
        } else if (hasB) {
            // rt = 0 (acc aA*), rt = 1 (acc aB*): h0(t) K-half completes them
            {
                const int row = l15;
                const int xr  = ((row & 15) << 4) ^ ((row & 1) << 8);
                const int rb  = row * 512;
#pragma unroll
                for (int kk = 0; kk < 8; ++kk) {
                    const int off = rb + ((q * 16 + kk * 64) ^ xr);
                    const half8 ah = *(const half8*)(pH0 + off);
                    aA0 = __builtin_amdgcn_mfma_f32_16x16x32_f16(ah, Bf0[8 + kk], aA0, 0,0,0);
                    aA1 = __builtin_amdgcn_mfma_f32_16x16x32_f16(ah, Bf1[8 + kk], aA1, 0,0,0);
                }
                gstore(gl0, 0, wl, q, l15, aA0, aA1);
            }
            {
                const int row = 16 + l15;
                const int xr  = ((row & 15) << 4) ^ ((row & 1) << 8);
                const int rb  = row * 512;
#pragma unroll
                for (int kk = 0; kk < 8; ++kk) {
                    const int off = rb + ((q * 16 + kk * 64) ^ xr);
                    const half8 ah = *(const half8*)(pH0 + off);
                    aB0 = __builtin_amdgcn_mfma_f32_16x16x32_f16(ah, Bf0[8 + kk], aB0, 0,0,0);
                    aB1 = __builtin_amdgcn_mfma_f32_16x16x32_f16(ah, Bf1[8 + kk], aB1, 0,0,0);
                }
                gstore(gl0, 1, wl, q, l15, aB0, aB1);
            }
            cells_wave(gl0, grow, gcb, bs, cst,
                       (_Float16*)(h0b + pn + coff), nullptr);
        }

        // -- drain own h/u stores, converge, publish
        asm volatile("s_waitcnt vmcnt(0)" ::: "memory");
        __syncthreads();
        if (hasB && tid == 0)
            __hip_atomic_fetch_add(fslot, 1u, __ATOMIC_RELAXED,
                                   __HIP_MEMORY_SCOPE_AGENT);
    }
}

// ---------------- last layer: y = y2 @ Wo3^T + bo3, N=6, fp16 in -----------
__global__ __launch_bounds__(256)
void out_mlp3(const _Float16* __restrict__ y2, const float* __restrict__ Wo3,
              const float* __restrict__ bo3, float* __restrict__ out)
{
    const int lane = threadIdx.x & 63;
    const int row  = blockIdx.x * 4 + (threadIdx.x >> 6);
    const _Float16* yr = y2 + (size_t)row * kH + lane * 4;
    const float a0 = (float)yr[0], a1 = (float)yr[1], a2 = (float)yr[2], a3 = (float)yr[3];
    float s[kLag];
#pragma unroll
    for (int o = 0; o < kLag; ++o) {
        const float4 wv = *(const float4*)(Wo3 + o * kH + lane * 4);
        s[o] = a0 * wv.x + a1 * wv.y + a2 * wv.z + a3 * wv.w;
    }
#pragma unroll
    for (int off = 32; off > 0; off >>= 1) {
#pragma unroll
        for (int o = 0; o < kLag; ++o) s[o] += __shfl_down(s[o], off);
    }
    if (lane == 0) {
#pragma unroll
        for (int o = 0; o < kLag; ++o)
            out[(size_t)row * kLag + o] = s[o] + bo3[o];
    }
}

// ---------------------------------------------------------------------------
extern "C" void kernel_launch(void* const* d_in, const int* in_sizes, int n_in,
                              void* d_out, int out_size, void* d_ws, size_t ws_size,
                              hipStream_t stream)
{
    const float* x    = (const float*)d_in[0];
    const float* Wi1  = (const float*)d_in[1];
    const float* bi1  = (const float*)d_in[2];
    const float* Wi2  = (const float*)d_in[3];
    const float* bi2  = (const float*)d_in[4];
    const float* Wi3  = (const float*)d_in[5];
    const float* bi3  = (const float*)d_in[6];
    const float* Wih0 = (const float*)d_in[7];
    const float* Whh0 = (const float*)d_in[8];
    const float* bih0 = (const float*)d_in[9];
    const float* bhh0 = (const float*)d_in[10];
    const float* Wih1 = (const float*)d_in[11];
    const float* Whh1 = (const float*)d_in[12];
    const float* bih1 = (const float*)d_in[13];
    const float* bhh1 = (const float*)d_in[14];
    const float* Wo1  = (const float*)d_in[15];
    const float* bo1  = (const float*)d_in[16];
    const float* Wo2  = (const float*)d_in[17];
    const float* bo2  = (const float*)d_in[18];
    const float* Wo3  = (const float*)d_in[19];
    const float* bo3  = (const float*)d_in[20];
    float* outp = (float*)d_out;

    // ---- workspace layout (~106 MB) ----
    char* p = (char*)d_ws;
    _Float16* ubuf = (_Float16*)p;  p += (size_t)kT * kB * kH * 2;   // 67.1 MB
    _Float16* s1   = (_Float16*)p;  p += (size_t)kMc * kH * 2;       // 16.8 MB
    _Float16* s2   = (_Float16*)p;  p += (size_t)kMc * kH * 2;       // 16.8 MB
    _Float16* Wc0  = (_Float16*)p;  p += (size_t)1024 * 512 * 2;     // 1 MB
    _Float16* Wc1  = (_Float16*)p;  p += (size_t)1024 * 512 * 2;     // 1 MB
    _Float16* W2h  = (_Float16*)p;  p += (size_t)kH * kH * 2;
    _Float16* W3h  = (_Float16*)p;  p += (size_t)kH * kH * 2;
    _Float16* Wo1h = (_Float16*)p;  p += (size_t)kH * kH * 2;
    _Float16* Wo2h = (_Float16*)p;  p += (size_t)kH * kH * 2;
    float* bc0 = (float*)p;  p += 1024 * 4;
    float* bc1 = (float*)p;  p += 1024 * 4;
    // zeroed region: h double-buffers + flags/counters (contiguous)
    _Float16* h0b = (_Float16*)p;  p += (size_t)2 * kB * kH * 2;     // 1 MB
    _Float16* h1b = (_Float16*)p;  p += (size_t)2 * kB * kH * 2;     // 1 MB
    unsigned int* cnt = (unsigned int*)p;  p += kCntUints * 4;       // 64 KB

    // ---- prep: zero h0b(1MB)+h1b(1MB)+cnt(64KB) = 2112 x 1KB ----
    zero_fill<<<2112, 256, 0, stream>>>((unsigned int*)h0b);
    cvt_f2h<<<kH * kH / 256, 256, 0, stream>>>(Wi2, W2h);
    cvt_f2h<<<kH * kH / 256, 256, 0, stream>>>(Wi3, W3h);
    cvt_f2h<<<kH * kH / 256, 256, 0, stream>>>(Wo1, Wo1h);
    cvt_f2h<<<kH * kH / 256, 256, 0, stream>>>(Wo2, Wo2h);
    build_wcat3<<<1024 * 512 / 256, 256, 0, stream>>>(Wih0, Whh0, Wc0);
    build_wcat3<<<1024 * 512 / 256, 256, 0, stream>>>(Wih1, Whh1, Wc1);
    add_bias<<<4, 256, 0, stream>>>(bih0, bhh0, bc0);
    add_bias<<<4, 256, 0, stream>>>(bih1, bhh1, bc1);

    // ---- input MLP (chunked): x -> s1 -> s2 -> ubuf ----
    for (int c = 0; c < kT / kTc; ++c) {
        in_mlp1<<<kMc * kH / 256, 256, 0, stream>>>(
            x + (size_t)c * kMc * kLag, Wi1, bi1, s1);
        gemm_h16<<<dim3(4, kMc / 128), 256, 0, stream>>>(s1, W2h, bi2, s2);
        gemm_h16<<<dim3(4, kMc / 128), 256, 0, stream>>>(
            s2, W3h, bi3, ubuf + (size_t)c * kMc * kH);
    }

    // ---- LSTM: cooperative, 32 groups x 8 blocks, barrier-overlapped ----
    static bool attr_set = false;
    if (!attr_set) {
        hipFuncSetAttribute((const void*)lstm_all,
                            hipFuncAttributeMaxDynamicSharedMemorySize, kLdsForce);
        attr_set = true;
    }
    void* args[] = {&ubuf, &Wc0, &Wc1, &bc0, &bc1, &h0b, &h1b, &cnt};
    hipLaunchCooperativeKernel((const void*)lstm_all, dim3(256), dim3(512),
                               args, kLdsForce, stream);

    // ---- output MLP (chunked): ubuf -> s1 -> s2 -> out ----
    for (int c = 0; c < kT / kTc; ++c) {
        gemm_h16<<<dim3(4, kMc / 128), 256, 0, stream>>>(
            ubuf + (size_t)c * kMc * kH, Wo1h, bo1, s1);
        gemm_h16<<<dim3(4, kMc / 128), 256, 0, stream>>>(s1, Wo2h, bo2, s2);
        out_mlp3<<<kMc / 4, 256, 0, stream>>>(
            s2, Wo3, bo3, outp + (size_t)c * kMc * kLag);
    }
}

// Round 9
// 2051.645 us; speedup vs baseline: 1.0194x; 1.0194x over previous
//
#include <hip/hip_runtime.h>
#include <math.h>

// ---------------------------------------------------------------------------
// RNN_63153199120819 — Round 19: wave-async 2-chain pipeline (R18 redo).
// R18 post-mortem found a WAR race: with double-buffered h0, L0@t's write of
// h0(t+1) lands in the buffer L1@t-1 may still be READING (h0(t-1)), since
// L0 only waits f1>=t (L1 done t-2). Fix: h0 TRIPLE buffer — write target
// buf (t+1)%3 holds h0(t-2), whose readers are done under the same f1>=t.
// Also: R18 had 131K unthrottled LLC pollers (8x R13-17); poll loop now
// throttled with s_sleep(1) after a failed check (R10's proven idiom).
// Flag protocol (per-wave slots, LLC atomics): f0=k <=> h0(k-1) ready;
// f1=k <=> h1(k-2) ready. L0@t: ugemm u(t+1) pre-poll -> poll(f0>=t+1,
// f1>=t) -> h0(t) frags (sc0) -> MFMA -> cells -> drain -> publish.
// L1@t: poll(f0>=t+1, f1>=t+1) -> [h0(t)|h1(t-1)] -> MFMA -> cells
// (h1 + relu u) -> drain -> publish. Deadlock-free by induction.
// ---------------------------------------------------------------------------

namespace {
constexpr int kT   = 128;
constexpr int kB   = 1024;
constexpr int kLag = 6;
constexpr int kH   = 256;
constexpr int kTc  = 32;          // MLP time chunk
constexpr int kMc  = kTc * kB;    // 32768 rows / chunk
constexpr int kGS  = 132;         // gl row stride (f32): 4-bank skew, 0-conflict (R16/17)
constexpr int kLdsForce = 98304;  // force 1 block/CU (rank discovery relies on it)
constexpr int kRankMain = 32768;  // cnt[] uint idx; flags [0, 32*1024)
constexpr int kCntUints = 36864;  // zeroed: 144KB
}

typedef _Float16 half8 __attribute__((ext_vector_type(8)));
typedef _Float16 half4 __attribute__((ext_vector_type(4)));
typedef float f32x4 __attribute__((ext_vector_type(4)));
typedef unsigned long long u64;

__device__ __forceinline__ float sigm(float x) {
    return 1.f / (1.f + exp2f(-1.4426950408889634f * x));
}
__device__ __forceinline__ float tanh_(float x) {
    return 2.f / (1.f + exp2f(-2.8853900817779268f * x)) - 1.f;
}

// ---- inline-asm memory ops ------------------------------------------------
__device__ __forceinline__ void ld_l2(half8& d, const _Float16* p) {
    asm volatile("global_load_dwordx4 %0, %1, off sc0"
                 : "=v"(d) : "v"(p) : "memory");
}
#define WAITCNT_HOLD16(A)                                                     \
    asm volatile("s_waitcnt vmcnt(0)"                                         \
        : "+v"(A[0]), "+v"(A[1]), "+v"(A[2]), "+v"(A[3]),                     \
          "+v"(A[4]), "+v"(A[5]), "+v"(A[6]), "+v"(A[7]),                     \
          "+v"(A[8]), "+v"(A[9]), "+v"(A[10]), "+v"(A[11]),                   \
          "+v"(A[12]), "+v"(A[13]), "+v"(A[14]), "+v"(A[15]))

// ---------------- prep kernels ---------------------------------------------
__global__ __launch_bounds__(256)
void zero_fill(unsigned int* __restrict__ p)
{
    p[blockIdx.x * 256 + threadIdx.x] = 0u;
}

__global__ __launch_bounds__(256)
void cvt_f2h(const float* __restrict__ s, _Float16* __restrict__ d)
{
    const int i = blockIdx.x * 256 + threadIdx.x;
    d[i] = (_Float16)s[i];
}

// gate-interleaved Wc: new row r = hcol*4 + g  <-  old row g*256 + hcol.
__global__ __launch_bounds__(256)
void build_wcat3(const float* __restrict__ Wih, const float* __restrict__ Whh,
                 _Float16* __restrict__ d)
{
    const int i = blockIdx.x * 256 + threadIdx.x;   // over 1024*512
    const int row = i >> 9, col = i & 511;
    const int src = (row & 3) * 256 + (row >> 2);
    const float v = (col < 256) ? Wih[src * 256 + col] : Whh[src * 256 + col - 256];
    d[i] = (_Float16)v;
}

__global__ __launch_bounds__(256)
void add_bias(const float* __restrict__ a, const float* __restrict__ b,
              float* __restrict__ d)
{
    const int i = blockIdx.x * 256 + threadIdx.x;
    d[i] = a[i] + b[i];
}

// ---------------- first layer: u1 = relu(x @ Wi1^T + bi1), K=6, fp16 out ---
__global__ __launch_bounds__(256)
void in_mlp1(const float* __restrict__ x, const float* __restrict__ Wi1,
             const float* __restrict__ bi1, _Float16* __restrict__ out)
{
    const int idx = blockIdx.x * 256 + threadIdx.x;   // over Mc*H
    const int col = idx & (kH - 1);
    const int row = idx >> 8;
    const float* xr = x + (size_t)row * kLag;
    const float* w  = Wi1 + col * kLag;
    float s = bi1[col];
#pragma unroll
    for (int k = 0; k < kLag; ++k) s = fmaf(xr[k], w[k], s);
    out[idx] = (_Float16)fmaxf(s, 0.f);
}

// ---------------- fp16 MFMA GEMM v2 (unchanged, validated) -----------------
__global__ __launch_bounds__(256)
void gemm_h16(const _Float16* __restrict__ A, const _Float16* __restrict__ W,
              const float* __restrict__ bias, _Float16* __restrict__ C)
{
    const int tid = threadIdx.x;
    const int w = tid >> 6, lane = tid & 63, q = lane >> 4, l15 = lane & 15;
    const int n0 = blockIdx.x * 64;
    const int r0 = blockIdx.y * 128 + w * 32;

    half8 bf[4][8];
#pragma unroll
    for (int nt = 0; nt < 4; ++nt)
#pragma unroll
        for (int kk = 0; kk < 8; ++kk)
            bf[nt][kk] = *(const half8*)(W + (size_t)(n0 + nt * 16 + l15) * 256
                                         + kk * 32 + q * 8);
    float bz[4];
#pragma unroll
    for (int nt = 0; nt < 4; ++nt) bz[nt] = bias[n0 + nt * 16 + l15];

#pragma unroll
    for (int rt = 0; rt < 2; ++rt) {
        const _Float16* arow = A + (size_t)(r0 + rt * 16 + l15) * 256 + q * 8;
        half8 af[8];
#pragma unroll
        for (int kk = 0; kk < 8; ++kk) af[kk] = *(const half8*)(arow + kk * 32);
        f32x4 acc[4];
#pragma unroll
        for (int nt = 0; nt < 4; ++nt)
            acc[nt] = (f32x4){bz[nt], bz[nt], bz[nt], bz[nt]};
#pragma unroll
        for (int kk = 0; kk < 8; ++kk)
#pragma unroll
            for (int nt = 0; nt < 4; ++nt)
                acc[nt] = __builtin_amdgcn_mfma_f32_16x16x32_f16(
                    af[kk], bf[nt][kk], acc[nt], 0, 0, 0);
#pragma unroll
        for (int nt = 0; nt < 4; ++nt)
#pragma unroll
            for (int r = 0; r < 4; ++r) {
                const float v = fmaxf(acc[nt][r], 0.f);
                C[(size_t)(r0 + rt * 16 + q * 4 + r) * 256 + n0 + nt * 16 + l15]
                    = (_Float16)v;
            }
    }
}

// ---------------- persistent LSTM helpers ----------------------------------
// per-wave poll, throttled: 64 lanes cover 64 slots (0..31 f0>=tlo, 32..63
// f1>=thi); s_sleep(1) after a failed check (R10's proven idiom).
__device__ __forceinline__ void pollw(const unsigned int* __restrict__ fb,
                                      unsigned int tlo, unsigned int thi,
                                      int lane)
{
    const unsigned int* fp = fb + lane * 16;   // 64B-padded slots
    const unsigned int tgt = (lane < 32) ? tlo : thi;
    while (true) {
        const unsigned int v =
            __hip_atomic_load(fp, __ATOMIC_RELAXED, __HIP_MEMORY_SCOPE_AGENT);
        if (!__any(v < tgt)) break;
        __builtin_amdgcn_s_sleep(1);
    }
}

// MFMA C layout: col=l15, row=q*4+r. Wave's gate cols: wl*32 + tile*16 + l15.
__device__ __forceinline__ void gstore(float* __restrict__ gl, int rt, int wl,
                                       int q, int l15,
                                       const f32x4& a0, const f32x4& a1)
{
#pragma unroll
    for (int r = 0; r < 4; ++r) {
        gl[(rt*16 + q*4 + r) * kGS + wl*32 + l15]      = a0[r];
        gl[(rt*16 + q*4 + r) * kGS + wl*32 + 16 + l15] = a1[r];
    }
}

// u K-half GEMM for both row-tiles (plain loads; peer-independent)
__device__ __forceinline__ void ugemm(const _Float16* __restrict__ u,
    const half8 (&B0)[16], const half8 (&B1)[16], int q, int l15,
    f32x4& aA0, f32x4& aA1, f32x4& aB0, f32x4& aB1)
{
    {
        const _Float16* pu = u + (size_t)l15 * 256 + q * 8;
        half8 uf[8];
#pragma unroll
        for (int kk = 0; kk < 8; ++kk) uf[kk] = *(const half8*)(pu + kk * 32);
#pragma unroll
        for (int kk = 0; kk < 8; ++kk) {
            aA0 = __builtin_amdgcn_mfma_f32_16x16x32_f16(uf[kk], B0[kk], aA0, 0,0,0);
            aA1 = __builtin_amdgcn_mfma_f32_16x16x32_f16(uf[kk], B1[kk], aA1, 0,0,0);
        }
    }
    {
        const _Float16* pu = u + (size_t)(16 + l15) * 256 + q * 8;
        half8 uf[8];
#pragma unroll
        for (int kk = 0; kk < 8; ++kk) uf[kk] = *(const half8*)(pu + kk * 32);
#pragma unroll
        for (int kk = 0; kk < 8; ++kk) {
            aB0 = __builtin_amdgcn_mfma_f32_16x16x32_f16(uf[kk], B0[kk], aB0, 0,0,0);
            aB1 = __builtin_amdgcn_mfma_f32_16x16x32_f16(uf[kk], B1[kk], aB1, 0,0,0);
        }
    }
}

// per-wave cells: 4 cells/lane; gates at gl[grow][gcb + c*4 + g] (f32x4).
__device__ __forceinline__ void cells_wave(const float* __restrict__ gl,
    int grow, int gcb, const float* __restrict__ bs, float* __restrict__ cst,
    _Float16* __restrict__ hout, _Float16* __restrict__ uout)
{
    const float* gr = gl + grow * kGS + gcb;
    half4 hv;
#pragma unroll
    for (int c = 0; c < 4; ++c) {
        const f32x4 g4 = *(const f32x4*)(gr + c * 4);   // gates i,f,g,o
        const float gi = g4[0] + bs[c*4 + 0];
        const float gf = g4[1] + bs[c*4 + 1];
        const float gg = g4[2] + bs[c*4 + 2];
        const float go = g4[3] + bs[c*4 + 3];
        const float c2 = sigm(gf) * cst[c] + sigm(gi) * tanh_(gg);
        cst[c] = c2;
        hv[c] = (_Float16)(sigm(go) * tanh_(c2));
    }
    *(half4*)hout = hv;
    if (uout) {
        const _Float16 z = (_Float16)0.f;
        half4 uv;
#pragma unroll
        for (int c = 0; c < 4; ++c) uv[c] = hv[c] > z ? hv[c] : z;
        *(half4*)uout = uv;
    }
}

// ---------------- persistent LSTM kernel -----------------------------------
// 256 blocks = 32 groups x 8. Group bi owns batch rows [bi*32, bi*32+32).
// Block js owns h-cols [js*32, js*32+32). Per-wave flags: slot js*4+wl
// (flag0, layer-0 waves) / 32 + js*4 + wl (flag1, layer-1 waves).
// h0b: TRIPLE buffer (phase t: read buf t%3, write buf (t+1)%3).
__global__ __launch_bounds__(512, 2)
void lstm_all(_Float16* __restrict__ ubuf,
              const _Float16* __restrict__ Wc0, const _Float16* __restrict__ Wc1,
              const float* __restrict__ bc0, const float* __restrict__ bc1,
              _Float16* __restrict__ h0b, _Float16* __restrict__ h1b,
              unsigned int* __restrict__ cnt)
{
    extern __shared__ char lds[];
    float* gl0 = (float*)lds;             // [32][kGS] layer-0 gates (wave-private cols)
    float* gl1 = gl0 + 32 * kGS;          // [32][kGS] layer-1 gates

    const int tid = threadIdx.x;
    const int w = tid >> 6, lane = tid & 63, q = lane >> 4, l15 = lane & 15;
    const int wl = w & 3;                 // wave's col-slice within layer
    const int lyr = (w < 4) ? 1 : 0;      // wave's layer

    // ---- XCD discovery: 1 block/CU (forced LDS) => 32 blocks/XCD ----
    __shared__ int sh_bi, sh_js;
    if (tid == 0) {
        unsigned int xcd = __builtin_amdgcn_s_getreg(20 | (31 << 11)) & 7u;
        unsigned int rank = __hip_atomic_fetch_add(cnt + kRankMain + xcd * 16, 1u,
            __ATOMIC_RELAXED, __HIP_MEMORY_SCOPE_AGENT);
        sh_bi = (int)(xcd * 4 + (rank >> 3));
        sh_js = (int)(rank & 7);
    }
    __syncthreads();
    const int bi = sh_bi, js = sh_js;
    unsigned int* fb    = cnt + (size_t)bi * 1024;          // 64 slots x 64B
    unsigned int* fslot = fb + (lyr ? (32 + js*4 + wl) : (js*4 + wl)) * 16;

    // ---- B-fragments: gate rows js*128 + wl*32 + tile*16 + l15 ----
    const _Float16* WcL = lyr ? Wc1 : Wc0;
    half8 Bf0[16], Bf1[16];
    {
        const _Float16* wr0 = WcL + (size_t)(js*128 + wl*32 + l15) * 512 + q * 8;
        const _Float16* wr1 = wr0 + (size_t)16 * 512;
#pragma unroll
        for (int kk = 0; kk < 16; ++kk) {
            Bf0[kk] = *(const half8*)(wr0 + kk * 32);
            Bf1[kk] = *(const half8*)(wr1 + kk * 32);
        }
    }

    // ---- per-lane cell geometry / biases / state ----
    const int grow = lane >> 1;                     // batch row 0..31
    const int gcb  = wl*32 + (lane & 1) * 16;       // gl gate-col base
    const int hcb  = js*32 + wl*8 + (lane & 1) * 4; // global h-col base
    const float* bcL = lyr ? bc1 : bc0;
    float bs[16];
#pragma unroll
    for (int c = 0; c < 4; ++c)
#pragma unroll
        for (int g = 0; g < 4; ++g)
            bs[c*4 + g] = bcL[g * 256 + hcb + c];
    float cst[4] = {0.f, 0.f, 0.f, 0.f};
    const size_t rbase = (size_t)bi * 32 * 256;
    const size_t coff  = rbase + (size_t)grow * 256 + hcb;

    // ---- prologue (per-wave, no block sync) ----
    if (lyr == 0) {
        // h0(0) = cell(u(0) @ W0-lo + bias), h=0 -> h0b buf 0
        f32x4 aA0 = {0.f,0.f,0.f,0.f}, aA1 = {0.f,0.f,0.f,0.f};
        f32x4 aB0 = {0.f,0.f,0.f,0.f}, aB1 = {0.f,0.f,0.f,0.f};
        ugemm(ubuf + rbase, Bf0, Bf1, q, l15, aA0, aA1, aB0, aB1);
        gstore(gl0, 0, wl, q, l15, aA0, aA1);
        gstore(gl0, 1, wl, q, l15, aB0, aB1);
        cells_wave(gl0, grow, gcb, bs, cst, (_Float16*)(h0b + coff), nullptr);
        asm volatile("s_waitcnt vmcnt(0)" ::: "memory");
        if (lane == 0)
            __hip_atomic_fetch_add(fslot, 1u, __ATOMIC_RELAXED,
                                   __HIP_MEMORY_SCOPE_AGENT);
    } else {
        // h1(-1) = zeros (pre-zeroed h1b parity 1): flag1 = 1 immediately
        if (lane == 0)
            __hip_atomic_fetch_add(fslot, 1u, __ATOMIC_RELAXED,
                                   __HIP_MEMORY_SCOPE_AGENT);
    }

    // ---- per-wave phases ----
    int bufr = 0;                                    // t % 3
    for (int t = 0; t < kT; ++t) {
        const size_t b0r = (size_t)bufr * kB * 256;              // h0(t)
        const size_t b0w = (size_t)(bufr == 2 ? 0 : bufr + 1) * kB * 256; // h0(t+1)
        const size_t p  = (size_t)(t & 1) * kB * 256;            // h1(t)
        const size_t pn = (size_t)((t & 1) ^ 1) * kB * 256;      // h1(t-1)
        const bool hasB = (t < kT - 1);

        if (lyr == 1) {
            // needs h0(t) [f0 >= t+1] and h1(t-1) [f1 >= t+1]
            pollw(fb, (unsigned)(t + 1), (unsigned)(t + 1), lane);
            __builtin_amdgcn_sched_barrier(0);
            const char* h0p = (const char*)(h0b + b0r + rbase);
            const char* h1p = (const char*)(h1b + pn  + rbase);
#pragma unroll
            for (int rt = 0; rt < 2; ++rt) {
                const int rb = (rt*16 + l15) * 512 + q * 16;
                half8 A[16];
#pragma unroll
                for (int kk = 0; kk < 8; ++kk) {
                    ld_l2(A[kk],     (const _Float16*)(h0p + rb + kk * 64));
                    ld_l2(A[8 + kk], (const _Float16*)(h1p + rb + kk * 64));
                }
                WAITCNT_HOLD16(A);
                f32x4 a0 = {0.f,0.f,0.f,0.f}, a1 = {0.f,0.f,0.f,0.f};
#pragma unroll
                for (int kk = 0; kk < 8; ++kk) {
                    a0 = __builtin_amdgcn_mfma_f32_16x16x32_f16(A[kk], Bf0[kk],         a0, 0,0,0);
                    a1 = __builtin_amdgcn_mfma_f32_16x16x32_f16(A[kk], Bf1[kk],         a1, 0,0,0);
                    a0 = __builtin_amdgcn_mfma_f32_16x16x32_f16(A[8 + kk], Bf0[8 + kk], a0, 0,0,0);
                    a1 = __builtin_amdgcn_mfma_f32_16x16x32_f16(A[8 + kk], Bf1[8 + kk], a1, 0,0,0);
                }
                gstore(gl1, rt, wl, q, l15, a0, a1);
            }
            cells_wave(gl1, grow, gcb, bs, cst,
                       (_Float16*)(h1b + p + coff),
                       (_Float16*)(ubuf + (size_t)t * kB * 256 + coff));
            asm volatile("s_waitcnt vmcnt(0)" ::: "memory");
            if (lane == 0)
                __hip_atomic_fetch_add(fslot, 1u, __ATOMIC_RELAXED,
                                       __HIP_MEMORY_SCOPE_AGENT);
        } else if (hasB) {
            // pre-poll: u(t+1) K-half (peer-independent; WAR-safe: L1@t+1
            // needs f0>=t+2, published only after these reads drain)
            f32x4 aA0 = {0.f,0.f,0.f,0.f}, aA1 = {0.f,0.f,0.f,0.f};
            f32x4 aB0 = {0.f,0.f,0.f,0.f}, aB1 = {0.f,0.f,0.f,0.f};
            ugemm(ubuf + (size_t)(t + 1) * kB * 256 + rbase,
                  Bf0, Bf1, q, l15, aA0, aA1, aB0, aB1);
            // needs h0(t) [f0 >= t+1]; WAR on h0 buf (t+1)%3 (= h0(t-2)):
            // its readers L1@t-2 done under [f1 >= t]
            pollw(fb, (unsigned)(t + 1), (unsigned)t, lane);
            __builtin_amdgcn_sched_barrier(0);
            const char* h0p = (const char*)(h0b + b0r + rbase);
            half8 Hh[16];
#pragma unroll
            for (int kk = 0; kk < 8; ++kk) {
                ld_l2(Hh[kk],     (const _Float16*)(h0p + l15 * 512        + q * 16 + kk * 64));
                ld_l2(Hh[8 + kk], (const _Float16*)(h0p + (16 + l15) * 512 + q * 16 + kk * 64));
            }
            WAITCNT_HOLD16(Hh);
#pragma unroll
            for (int kk = 0; kk < 8; ++kk) {
                aA0 = __builtin_amdgcn_mfma_f32_16x16x32_f16(Hh[kk], Bf0[8 + kk],     aA0, 0,0,0);
                aA1 = __builtin_amdgcn_mfma_f32_16x16x32_f16(Hh[kk], Bf1[8 + kk],     aA1, 0,0,0);
                aB0 = __builtin_amdgcn_mfma_f32_16x16x32_f16(Hh[8 + kk], Bf0[8 + kk], aB0, 0,0,0);
                aB1 = __builtin_amdgcn_mfma_f32_16x16x32_f16(Hh[8 + kk], Bf1[8 + kk], aB1, 0,0,0);
            }
            gstore(gl0, 0, wl, q, l15, aA0, aA1);
            gstore(gl0, 1, wl, q, l15, aB0, aB1);
            cells_wave(gl0, grow, gcb, bs, cst,
                       (_Float16*)(h0b + b0w + coff), nullptr);
            asm volatile("s_waitcnt vmcnt(0)" ::: "memory");
            if (lane == 0)
                __hip_atomic_fetch_add(fslot, 1u, __ATOMIC_RELAXED,
                                       __HIP_MEMORY_SCOPE_AGENT);
        }
        bufr = (bufr == 2) ? 0 : bufr + 1;
    }
}

// ---------------- last layer: y = y2 @ Wo3^T + bo3, N=6, fp16 in -----------
__global__ __launch_bounds__(256)
void out_mlp3(const _Float16* __restrict__ y2, const float* __restrict__ Wo3,
              const float* __restrict__ bo3, float* __restrict__ out)
{
    const int lane = threadIdx.x & 63;
    const int row  = blockIdx.x * 4 + (threadIdx.x >> 6);
    const _Float16* yr = y2 + (size_t)row * kH + lane * 4;
    const float a0 = (float)yr[0], a1 = (float)yr[1], a2 = (float)yr[2], a3 = (float)yr[3];
    float s[kLag];
#pragma unroll
    for (int o = 0; o < kLag; ++o) {
        const float4 wv = *(const float4*)(Wo3 + o * kH + lane * 4);
        s[o] = a0 * wv.x + a1 * wv.y + a2 * wv.z + a3 * wv.w;
    }
#pragma unroll
    for (int off = 32; off > 0; off >>= 1) {
#pragma unroll
        for (int o = 0; o < kLag; ++o) s[o] += __shfl_down(s[o], off);
    }
    if (lane == 0) {
#pragma unroll
        for (int o = 0; o < kLag; ++o)
            out[(size_t)row * kLag + o] = s[o] + bo3[o];
    }
}

// ---------------------------------------------------------------------------
extern "C" void kernel_launch(void* const* d_in, const int* in_sizes, int n_in,
                              void* d_out, int out_size, void* d_ws, size_t ws_size,
                              hipStream_t stream)
{
    const float* x    = (const float*)d_in[0];
    const float* Wi1  = (const float*)d_in[1];
    const float* bi1  = (const float*)d_in[2];
    const float* Wi2  = (const float*)d_in[3];
    const float* bi2  = (const float*)d_in[4];
    const float* Wi3  = (const float*)d_in[5];
    const float* bi3  = (const float*)d_in[6];
    const float* Wih0 = (const float*)d_in[7];
    const float* Whh0 = (const float*)d_in[8];
    const float* bih0 = (const float*)d_in[9];
    const float* bhh0 = (const float*)d_in[10];
    const float* Wih1 = (const float*)d_in[11];
    const float* Whh1 = (const float*)d_in[12];
    const float* bih1 = (const float*)d_in[13];
    const float* bhh1 = (const float*)d_in[14];
    const float* Wo1  = (const float*)d_in[15];
    const float* bo1  = (const float*)d_in[16];
    const float* Wo2  = (const float*)d_in[17];
    const float* bo2  = (const float*)d_in[18];
    const float* Wo3  = (const float*)d_in[19];
    const float* bo3  = (const float*)d_in[20];
    float* outp = (float*)d_out;

    // ---- workspace layout (~107 MB) ----
    char* p = (char*)d_ws;
    _Float16* ubuf = (_Float16*)p;  p += (size_t)kT * kB * kH * 2;   // 67.1 MB
    _Float16* s1   = (_Float16*)p;  p += (size_t)kMc * kH * 2;       // 16.8 MB
    _Float16* s2   = (_Float16*)p;  p += (size_t)kMc * kH * 2;       // 16.8 MB
    _Float16* Wc0  = (_Float16*)p;  p += (size_t)1024 * 512 * 2;     // 1 MB
    _Float16* Wc1  = (_Float16*)p;  p += (size_t)1024 * 512 * 2;     // 1 MB
    _Float16* W2h  = (_Float16*)p;  p += (size_t)kH * kH * 2;
    _Float16* W3h  = (_Float16*)p;  p += (size_t)kH * kH * 2;
    _Float16* Wo1h = (_Float16*)p;  p += (size_t)kH * kH * 2;
    _Float16* Wo2h = (_Float16*)p;  p += (size_t)kH * kH * 2;
    float* bc0 = (float*)p;  p += 1024 * 4;
    float* bc1 = (float*)p;  p += 1024 * 4;
    // zeroed region: h0 triple buffer + h1 double buffer + flags (contiguous)
    _Float16* h0b = (_Float16*)p;  p += (size_t)3 * kB * kH * 2;     // 1.5 MB
    _Float16* h1b = (_Float16*)p;  p += (size_t)2 * kB * kH * 2;     // 1 MB
    unsigned int* cnt = (unsigned int*)p;  p += kCntUints * 4;       // 144 KB

    // ---- prep: zero h0b(1.5MB)+h1b(1MB)+cnt(144KB) = 2704 x 1KB ----
    zero_fill<<<2704, 256, 0, stream>>>((unsigned int*)h0b);
    cvt_f2h<<<kH * kH / 256, 256, 0, stream>>>(Wi2, W2h);
    cvt_f2h<<<kH * kH / 256, 256, 0, stream>>>(Wi3, W3h);
    cvt_f2h<<<kH * kH / 256, 256, 0, stream>>>(Wo1, Wo1h);
    cvt_f2h<<<kH * kH / 256, 256, 0, stream>>>(Wo2, Wo2h);
    build_wcat3<<<1024 * 512 / 256, 256, 0, stream>>>(Wih0, Whh0, Wc0);
    build_wcat3<<<1024 * 512 / 256, 256, 0, stream>>>(Wih1, Whh1, Wc1);
    add_bias<<<4, 256, 0, stream>>>(bih0, bhh0, bc0);
    add_bias<<<4, 256, 0, stream>>>(bih1, bhh1, bc1);

    // ---- input MLP (chunked): x -> s1 -> s2 -> ubuf ----
    for (int c = 0; c < kT / kTc; ++c) {
        in_mlp1<<<kMc * kH / 256, 256, 0, stream>>>(
            x + (size_t)c * kMc * kLag, Wi1, bi1, s1);
        gemm_h16<<<dim3(4, kMc / 128), 256, 0, stream>>>(s1, W2h, bi2, s2);
        gemm_h16<<<dim3(4, kMc / 128), 256, 0, stream>>>(
            s2, W3h, bi3, ubuf + (size_t)c * kMc * kH);
    }

    // ---- LSTM: cooperative, wave-async 2-chain pipeline ----
    static bool attr_set = false;
    if (!attr_set) {
        hipFuncSetAttribute((const void*)lstm_all,
                            hipFuncAttributeMaxDynamicSharedMemorySize, kLdsForce);
        attr_set = true;
    }
    void* args[] = {&ubuf, &Wc0, &Wc1, &bc0, &bc1, &h0b, &h1b, &cnt};
    hipLaunchCooperativeKernel((const void*)lstm_all, dim3(256), dim3(512),
                               args, kLdsForce, stream);

    // ---- output MLP (chunked): ubuf -> s1 -> s2 -> out ----
    for (int c = 0; c < kT / kTc; ++c) {
        gemm_h16<<<dim3(4, kMc / 128), 256, 0, stream>>>(
            ubuf + (size_t)c * kMc * kH, Wo1h, bo1, s1);
        gemm_h16<<<dim3(4, kMc / 128), 256, 0, stream>>>(s1, Wo2h, bo2, s2);
        out_mlp3<<<kMc / 4, 256, 0, stream>>>(
            s2, Wo3, bo3, outp + (size_t)c * kMc * kLag);
    }
}